// Round 5
// baseline (1638.723 us; speedup 1.0000x reference)
//
#include <hip/hip_runtime.h>
#include <math.h>

// Problem constants (from reference)
#define TT 2048
#define BB 512
#define II 11
#define HH 33
#define NL 3
#define OO 18
#define HSLOT 48          // halves per LDS vector slot (96 B, 16B-aligned slots)
#define WG 40             // halves per gate slot in weight stage (80 B, aligned)
#define WSLICE 160        // halves per lane per weight side (4 gates x 40)

typedef _Float16 h2 __attribute__((ext_vector_type(2)));
typedef _Float16 h8 __attribute__((ext_vector_type(8)));   // 16 B -> ds_read_b128

// fast sigmoid / tanh via v_exp_f32 + v_rcp_f32 (saturate correctly at +-inf)
__device__ __forceinline__ float sigm_f(float x) {
    float e = __expf(-x);
    return __builtin_amdgcn_rcpf(1.0f + e);
}
__device__ __forceinline__ float tanh_f(float x) {
    float e = __expf(2.0f * x);
    return 1.0f - 2.0f * __builtin_amdgcn_rcpf(e + 1.0f);
}

// guarded fp32->fp16 row-slice loads (zero-pad past rem)
__device__ __forceinline__ h8 gldh8(const float* p, int k0, int rem) {
    h8 v;
    #pragma unroll
    for (int i = 0; i < 8; ++i) v[i] = (_Float16)((k0 + i < rem) ? p[k0 + i] : 0.0f);
    return v;
}
__device__ __forceinline__ h2 gldh2(const float* p, int k0, int rem) {
    h2 v;
    v.x = (_Float16)((k0 + 0 < rem) ? p[k0 + 0] : 0.0f);
    v.y = (_Float16)((k0 + 1 < rem) ? p[k0 + 1] : 0.0f);
    return v;
}

// v_dot2_f32_f16: 2 MACs/op, fp32 accumulate
#define FD(a, p, q) a = __builtin_amdgcn_fdot2((p), (q), a, false)
// one 2-half slice fed to all 8 chains (4 input-side + 4 own-h-side)
#define DUO(vi_, vo_, SEL) do { \
    FD(a0i, (vi_).SEL, (xw0).SEL); FD(a1i, (vi_).SEL, (xw1).SEL); \
    FD(a2i, (vi_).SEL, (xw2).SEL); FD(a3i, (vi_).SEL, (xw3).SEL); \
    FD(a0h, (vo_).SEL, (hw0).SEL); FD(a1h, (vo_).SEL, (hw1).SEL); \
    FD(a2h, (vo_).SEL, (hw2).SEL); FD(a3h, (vo_).SEL, (hw3).SEL); } while (0)
#define DUOQ(vi_, vo_, xq0, xq1, xq2, xq3, hq0, hq1, hq2, hq3) do { \
    const h8 xw0 = (xq0), xw1 = (xq1), xw2 = (xq2), xw3 = (xq3); \
    const h8 hw0 = (hq0), hw1 = (hq1), hw2 = (hq2), hw3 = (hq3); \
    DUO(vi_, vo_, s01); DUO(vi_, vo_, s23); \
    DUO(vi_, vo_, s45); DUO(vi_, vo_, s67); } while (0)

// keep a register group pinned in ARCH VGPRs (no-op at runtime)
#define ANCHOR5(a, b, c, d, e) \
    asm volatile("" : "+v"(a), "+v"(b), "+v"(c), "+v"(d), "+v"(e))

// Layer-pipelined LSTM, ONE LANE PER UNIT, fused MLP head.
// grid = 512 blocks (one batch element), block = 128 threads (2 waves)
//   -> 1 wave/SIMD, deliberately: serial recurrence, co-resident waves only
//   contend for issue (R1/R3 measured worse at 2 waves/SIMD).
// KEY CHANGE vs R4: weight init is laundered through LDS. The old init
// (hundreds of hoisted guarded global loads + converts, all live at once)
// spiked register pressure >256, so the allocator birthed the 136 weight
// VGPRs into AGPRs -- and then every MAC in the 2050-step loop paid a hidden
// v_accvgpr_read (measured ~4.5cy effective per fdot2 across R0/R1/R3/R4
// instead of 2cy). Now: each lane writes its rows to a private LDS slice
// (transient pressure ~10 regs), then reads them back with sequential
// ds_read_b128 into named registers (monotone 0->136 growth, no spike),
// pinned with no-op "+v" asm anchors. Steady-loop live set ~205 < 256.
__global__ __launch_bounds__(128, 1) void lstm_pipeline_kernel(
    const float* __restrict__ x,
    const float* __restrict__ Wih0, const float* __restrict__ Whh0,
    const float* __restrict__ bih0, const float* __restrict__ bhh0,
    const float* __restrict__ Wih1, const float* __restrict__ Whh1,
    const float* __restrict__ bih1, const float* __restrict__ bhh1,
    const float* __restrict__ Wih2, const float* __restrict__ Whh2,
    const float* __restrict__ bih2, const float* __restrict__ bhh2,
    const float* __restrict__ W1, const float* __restrict__ b1,
    const float* __restrict__ W2, const float* __restrict__ b2,
    float* __restrict__ hidden_out,   // [3, 512, 33]
    float* __restrict__ outp)         // [3, 512, 18]
{
    __shared__ __align__(16) _Float16 buf[2][NL + 1][HSLOT];
    __shared__ __align__(16) _Float16 wstage[99][WSLICE];  // weight laundry
    __shared__ float hfin[NL][HH + 1];   // final h per layer (fp32, fused MLP)
    __shared__ float h1s[NL][4 * OO];    // MLP hidden

    const int tid = threadIdx.x;
    const int bg  = blockIdx.x;

    for (int i = tid; i < 2 * (NL + 1) * HSLOT; i += 128)
        ((_Float16*)buf)[i] = (_Float16)0.0f;

    const bool comp = (tid < 99);
    const int  u    = tid;
    const int  l    = (u < 33) ? 0 : (u < 66) ? 1 : 2;
    const int  j    = u - 33 * l;

    const int  pi   = tid - 99;
    const bool pref = (pi >= 0) && (pi < II);
    const float* xrow = x + (size_t)bg * TT * II + (pref ? pi : 0);

    // ---- per-lane weights: 4 gates x (input 34 + own 34) halves, named regs ----
    h8 z8 = {0,0,0,0,0,0,0,0};
    h2 z2 = {(_Float16)0.0f, (_Float16)0.0f};
    h8 x00=z8,x01=z8,x02=z8,x03=z8; h2 x0t=z2;   // gate i, input side (W_ih row)
    h8 x10=z8,x11=z8,x12=z8,x13=z8; h2 x1t=z2;   // gate f
    h8 x20=z8,x21=z8,x22=z8,x23=z8; h2 x2t=z2;   // gate g
    h8 x30=z8,x31=z8,x32=z8,x33=z8; h2 x3t=z2;   // gate o
    h8 h00=z8,h01=z8,h02=z8,h03=z8; h2 h0t=z2;   // gate i, own-h side (W_hh row)
    h8 h10=z8,h11=z8,h12=z8,h13=z8; h2 h1t=z2;
    h8 h20=z8,h21=z8,h22=z8,h23=z8; h2 h2t=z2;
    h8 h30=z8,h31=z8,h32=z8,h33=z8; h2 h3t=z2;
    float b0 = 0.0f, b1v = 0.0f, b2v = 0.0f, b3v = 0.0f;

    const int kin = (l == 0) ? II : HH;

    if (comp) {
        const float* bip = (l == 0) ? bih0 : (l == 1) ? bih1 : bih2;
        const float* bhp = (l == 0) ? bhh0 : (l == 1) ? bhh1 : bhh2;
        b0  = bip[0 * HH + j] + bhp[0 * HH + j];
        b1v = bip[1 * HH + j] + bhp[1 * HH + j];
        b2v = bip[2 * HH + j] + bhp[2 * HH + j];
        b3v = bip[3 * HH + j] + bhp[3 * HH + j];
    }

    // ---- weight stage, side A: W_ih rows (low transient pressure) ----
    if (comp) {
        const float* Wi = (l == 0) ? Wih0 : (l == 1) ? Wih1 : Wih2;
        _Float16* ws = &wstage[u][0];
        #pragma unroll
        for (int g = 0; g < 4; ++g) {
            const float* r = Wi + (g * HH + j) * kin;
            *(h8*)(ws + g * WG + 0)  = gldh8(r, 0,  kin);
            *(h8*)(ws + g * WG + 8)  = gldh8(r, 8,  kin);
            *(h8*)(ws + g * WG + 16) = gldh8(r, 16, kin);
            *(h8*)(ws + g * WG + 24) = gldh8(r, 24, kin);
            *(h2*)(ws + g * WG + 32) = gldh2(r, 32, kin);
        }
    }
    __syncthreads();
    if (comp) {
        const _Float16* ws = &wstage[u][0];
        x00 = *(const h8*)(ws + 0);   x01 = *(const h8*)(ws + 8);
        x02 = *(const h8*)(ws + 16);  x03 = *(const h8*)(ws + 24);
        x0t = *(const h2*)(ws + 32);
        ANCHOR5(x00, x01, x02, x03, x0t);
        x10 = *(const h8*)(ws + WG + 0);   x11 = *(const h8*)(ws + WG + 8);
        x12 = *(const h8*)(ws + WG + 16);  x13 = *(const h8*)(ws + WG + 24);
        x1t = *(const h2*)(ws + WG + 32);
        ANCHOR5(x10, x11, x12, x13, x1t);
        x20 = *(const h8*)(ws + 2 * WG + 0);   x21 = *(const h8*)(ws + 2 * WG + 8);
        x22 = *(const h8*)(ws + 2 * WG + 16);  x23 = *(const h8*)(ws + 2 * WG + 24);
        x2t = *(const h2*)(ws + 2 * WG + 32);
        ANCHOR5(x20, x21, x22, x23, x2t);
        x30 = *(const h8*)(ws + 3 * WG + 0);   x31 = *(const h8*)(ws + 3 * WG + 8);
        x32 = *(const h8*)(ws + 3 * WG + 16);  x33 = *(const h8*)(ws + 3 * WG + 24);
        x3t = *(const h2*)(ws + 3 * WG + 32);
        ANCHOR5(x30, x31, x32, x33, x3t);
    }
    __syncthreads();
    // ---- weight stage, side B: W_hh rows ----
    if (comp) {
        const float* Wh = (l == 0) ? Whh0 : (l == 1) ? Whh1 : Whh2;
        _Float16* ws = &wstage[u][0];
        #pragma unroll
        for (int g = 0; g < 4; ++g) {
            const float* r = Wh + (g * HH + j) * HH;
            *(h8*)(ws + g * WG + 0)  = gldh8(r, 0,  HH);
            *(h8*)(ws + g * WG + 8)  = gldh8(r, 8,  HH);
            *(h8*)(ws + g * WG + 16) = gldh8(r, 16, HH);
            *(h8*)(ws + g * WG + 24) = gldh8(r, 24, HH);
            *(h2*)(ws + g * WG + 32) = gldh2(r, 32, HH);
        }
    }
    __syncthreads();
    if (comp) {
        const _Float16* ws = &wstage[u][0];
        h00 = *(const h8*)(ws + 0);   h01 = *(const h8*)(ws + 8);
        h02 = *(const h8*)(ws + 16);  h03 = *(const h8*)(ws + 24);
        h0t = *(const h2*)(ws + 32);
        ANCHOR5(h00, h01, h02, h03, h0t);
        h10 = *(const h8*)(ws + WG + 0);   h11 = *(const h8*)(ws + WG + 8);
        h12 = *(const h8*)(ws + WG + 16);  h13 = *(const h8*)(ws + WG + 24);
        h1t = *(const h2*)(ws + WG + 32);
        ANCHOR5(h10, h11, h12, h13, h1t);
        h20 = *(const h8*)(ws + 2 * WG + 0);   h21 = *(const h8*)(ws + 2 * WG + 8);
        h22 = *(const h8*)(ws + 2 * WG + 16);  h23 = *(const h8*)(ws + 2 * WG + 24);
        h2t = *(const h2*)(ws + 2 * WG + 32);
        ANCHOR5(h20, h21, h22, h23, h2t);
        h30 = *(const h8*)(ws + 3 * WG + 0);   h31 = *(const h8*)(ws + 3 * WG + 8);
        h32 = *(const h8*)(ws + 3 * WG + 16);  h33 = *(const h8*)(ws + 3 * WG + 24);
        h3t = *(const h2*)(ws + 3 * WG + 32);
        ANCHOR5(h30, h31, h32, h33, h3t);
    }

    __syncthreads();
    float v_next = 0.0f, v_next2 = 0.0f;
    if (pref) {
        buf[0][0][pi] = (_Float16)xrow[0];
        v_next  = xrow[II];
        v_next2 = xrow[2 * II];
    }
    __syncthreads();

    float c = 0.0f;

    // hoisted ping-pong pointers (compile-time selected in peeled steps)
    const _Float16* rin[2]  = { &buf[0][l][0],     &buf[1][l][0] };      // input vec
    const _Float16* rown[2] = { &buf[0][l + 1][0], &buf[1][l + 1][0] };  // own-h vec
    _Float16*       wrp[2]  = { &buf[0][l + 1][j], &buf[1][l + 1][j] };
    _Float16*       pxp[2]  = { &buf[0][0][pi],    &buf[1][0][pi] };

    // one superstep; all bool/int args are compile-time constants at call sites
    auto step = [&](int s, int rp, bool check, bool out, bool xload, bool xstore)
        __attribute__((always_inline)) {
        const int wp = rp ^ 1;
        if (pref) {
            if (xstore) *pxp[wp] = (_Float16)v_next;
            v_next = v_next2;
            if (xload) v_next2 = xrow[(size_t)(s + 3) * II];
        }
        const bool active = check ? (comp && (s >= l) && (s - l < TT)) : comp;
        if (active) {
            const h8* VI = (const h8*)rin[rp];
            const h8 vi0 = VI[0], vi1 = VI[1], vi2 = VI[2], vi3 = VI[3];
            const h2 vit = *(const h2*)(rin[rp] + 32);
            const h8* VO = (const h8*)rown[rp];
            const h8 vo0 = VO[0], vo1 = VO[1], vo2 = VO[2], vo3 = VO[3];
            const h2 vot = *(const h2*)(rown[rp] + 32);

            // ---- single MAC phase: 8 independent 17-deep fdot2 chains ----
            float a0i = b0, a1i = b1v, a2i = b2v, a3i = b3v;
            float a0h = 0.0f, a1h = 0.0f, a2h = 0.0f, a3h = 0.0f;
            DUOQ(vi0, vo0, x00, x10, x20, x30, h00, h10, h20, h30);
            DUOQ(vi1, vo1, x01, x11, x21, x31, h01, h11, h21, h31);
            DUOQ(vi2, vo2, x02, x12, x22, x32, h02, h12, h22, h32);
            DUOQ(vi3, vo3, x03, x13, x23, x33, h03, h13, h23, h33);
            FD(a0i, vit, x0t); FD(a1i, vit, x1t);
            FD(a2i, vit, x2t); FD(a3i, vit, x3t);
            FD(a0h, vot, h0t); FD(a1h, vot, h1t);
            FD(a2h, vot, h2t); FD(a3h, vot, h3t);

            const float s0 = a0i + a0h;   // gate i
            const float s1 = a1i + a1h;   // gate f
            const float s2 = a2i + a2h;   // gate g
            const float s3 = a3i + a3h;   // gate o

            // ---- tail: 4 independent trans chains, then the c/h chain ----
            const float ig = sigm_f(s0);
            const float fg = sigm_f(s1);
            const float gg = tanh_f(s2);
            const float og = sigm_f(s3);
            c = __builtin_fmaf(fg, c, ig * gg);
            const float hnew = og * tanh_f(c);

            *wrp[wp] = (_Float16)hnew;
            if (out && (s - l == TT - 1)) {
                hidden_out[((size_t)l * BB + bg) * HH + j] = hnew;
                hfin[l][j] = hnew;
            }
        }
        __syncthreads();
    };

    // prologue (pipeline fill, masked)
    step(0, 0, true, false, true, true);
    step(1, 1, true, false, true, true);
    // steady state: s = 2..2043 as constant-rp pairs (no checks, no outputs)
    for (int s = 2; s < TT - 4; s += 2) {
        step(s,     0, false, false, true, true);
        step(s + 1, 1, false, false, true, true);
    }
    // tail of steady state + epilogue (drain + final-h outputs)
    step(TT - 4, 0, false, false, true,  true);    // s=2044 (last x load)
    step(TT - 3, 1, false, false, false, true);    // s=2045
    step(TT - 2, 0, false, false, false, true);    // s=2046 (stores x[2047])
    step(TT - 1, 1, false, true,  false, false);   // s=2047: l0 writes hT
    step(TT,     0, true,  true,  false, false);   // s=2048: l1 writes hT
    step(TT + 1, 1, true,  true,  false, false);   // s=2049: l2 writes hT

    // ---- fused MLP head (hfin visible after the last step's barrier) ----
    // h1 = gelu_exact(hfin @ W1^T + b1) [3,72]; out = h1 @ W2^T + b2 [3,18]
    if (tid < 4 * OO) {                   // 72 threads x 3 layers
        #pragma unroll
        for (int ml = 0; ml < NL; ++ml) {
            float a = b1[tid];
            #pragma unroll
            for (int k = 0; k < HH; ++k) a += hfin[ml][k] * W1[tid * HH + k];
            h1s[ml][tid] = 0.5f * a * (1.0f + erff(a * 0.70710678118654752f));
        }
    }
    __syncthreads();
    if (tid < NL * OO) {                  // 54 threads
        const int ol = tid / OO, o = tid % OO;
        float a = b2[o];
        #pragma unroll
        for (int m = 0; m < 4 * OO; ++m) a += h1s[ol][m] * W2[o * (4 * OO) + m];
        outp[((size_t)ol * BB + bg) * OO + o] = a;
    }
}

extern "C" void kernel_launch(void* const* d_in, const int* in_sizes, int n_in,
                              void* d_out, int out_size, void* d_ws, size_t ws_size,
                              hipStream_t stream) {
    const float* x    = (const float*)d_in[0];
    const float* Wih0 = (const float*)d_in[1];
    const float* Whh0 = (const float*)d_in[2];
    const float* bih0 = (const float*)d_in[3];
    const float* bhh0 = (const float*)d_in[4];
    const float* Wih1 = (const float*)d_in[5];
    const float* Whh1 = (const float*)d_in[6];
    const float* bih1 = (const float*)d_in[7];
    const float* bhh1 = (const float*)d_in[8];
    const float* Wih2 = (const float*)d_in[9];
    const float* Whh2 = (const float*)d_in[10];
    const float* bih2 = (const float*)d_in[11];
    const float* bhh2 = (const float*)d_in[12];
    const float* W1   = (const float*)d_in[13];
    const float* b1   = (const float*)d_in[14];
    const float* W2   = (const float*)d_in[15];
    const float* b2   = (const float*)d_in[16];

    float* out    = (float*)d_out;                 // [3,512,18] = 27648 floats
    float* hidden = out + NL * BB * OO;            // [3,512,33] = 50688 floats

    lstm_pipeline_kernel<<<BB, 128, 0, stream>>>(
        x, Wih0, Whh0, bih0, bhh0, Wih1, Whh1, bih1, bhh1,
        Wih2, Whh2, bih2, bhh2, W1, b1, W2, b2, hidden, out);
}

// Round 6
// 1041.591 us; speedup vs baseline: 1.5733x; 1.5733x over previous
//
#include <hip/hip_runtime.h>
#include <math.h>

// Problem constants (from reference)
#define TT 2048
#define BB 512
#define II 11
#define HH 33
#define NL 3
#define OO 18
#define HSLOT 48          // halves per LDS vector slot (96 B, 16B-aligned slots)
#define XPAD 16           // halves per staged-x row (32 B, b128-aligned reads)

typedef _Float16 h2 __attribute__((ext_vector_type(2)));
typedef _Float16 h8 __attribute__((ext_vector_type(8)));   // 16 B -> ds_read_b128

// fast sigmoid / tanh via v_exp_f32 + v_rcp_f32 (saturate correctly at +-inf)
__device__ __forceinline__ float sigm_f(float x) {
    float e = __expf(-x);
    return __builtin_amdgcn_rcpf(1.0f + e);
}
__device__ __forceinline__ float tanh_f(float x) {
    float e = __expf(2.0f * x);
    return 1.0f - 2.0f * __builtin_amdgcn_rcpf(e + 1.0f);
}

// guarded fp32->fp16 row-slice loads (zero-pad past rem)
__device__ __forceinline__ h8 gldh8(const float* p, int k0, int rem) {
    h8 v;
    #pragma unroll
    for (int i = 0; i < 8; ++i) v[i] = (_Float16)((k0 + i < rem) ? p[k0 + i] : 0.0f);
    return v;
}
__device__ __forceinline__ h2 gldh2(const float* p, int k0, int rem) {
    h2 v;
    v.x = (_Float16)((k0 + 0 < rem) ? p[k0 + 0] : 0.0f);
    v.y = (_Float16)((k0 + 1 < rem) ? p[k0 + 1] : 0.0f);
    return v;
}

// v_dot2_f32_f16: 2 MACs/op, fp32 accumulate
#define FD(a, p, q) a = __builtin_amdgcn_fdot2((p), (q), a, false)
// one 2-half slice fed to all 8 chains (4 input-side + 4 own-h-side)
#define DUO(vi_, vo_, SEL) do { \
    FD(a0i, (vi_).SEL, (xw0).SEL); FD(a1i, (vi_).SEL, (xw1).SEL); \
    FD(a2i, (vi_).SEL, (xw2).SEL); FD(a3i, (vi_).SEL, (xw3).SEL); \
    FD(a0h, (vo_).SEL, (hw0).SEL); FD(a1h, (vo_).SEL, (hw1).SEL); \
    FD(a2h, (vo_).SEL, (hw2).SEL); FD(a3h, (vo_).SEL, (hw3).SEL); } while (0)
#define DUOQ(vi_, vo_, xq0, xq1, xq2, xq3, hq0, hq1, hq2, hq3) do { \
    const h8 xw0 = (xq0), xw1 = (xq1), xw2 = (xq2), xw3 = (xq3); \
    const h8 hw0 = (hq0), hw1 = (hq1), hw2 = (hq2), hw3 = (hq3); \
    DUO(vi_, vo_, s01); DUO(vi_, vo_, s23); \
    DUO(vi_, vo_, s45); DUO(vi_, vo_, s67); } while (0)

// Layer-pipelined LSTM, ONE LANE PER UNIT, fused MLP head.
// grid = 512 blocks (one batch element), block = 128 threads (2 waves),
// 1 wave/SIMD (serial recurrence; extra occupancy measured pure overhead).
//
// KEY CHANGE vs the 1052-us R4 baseline: ZERO global memory ops in the
// steady loop. Cross-round fit showed a constant ~830 cy/step stall, additive
// under every MAC/occupancy change -- the compiler emits
// `s_waitcnt vmcnt(0) lgkmcnt(0)` before every s_barrier, so the per-step
// x prefetch global load (intended to land 3 steps later) was drained at
// EVERY superstep barrier, serializing an L2/LLC round trip into the
// recurrence. Fix: stage the block's whole x into LDS (fp16, padded rows of
// 16 halves = 64 KB) in the prologue with coalesced float4 reads; layer-0
// lanes read xst[s] directly. Prefetch lanes + x ping-pong slot deleted.
// LDS ~67 KB/block -> still 2 blocks/CU (512 blocks in one pass).
//
// tid < 99 : unit u = tid, l = u/33, j = u%33. Lane holds all weights of its
// unit (4 gate rows x (input 34 + own 34) halves, fp16, R4 init form), reads
// input vec (xst[s] for l=0, buf slot l else) and own-h vec (slot l+1) from
// LDS (broadcast), runs 136 fdot2 as 8 independent 17-deep chains, then the
// gate nonlinearity + c/h locally. One barrier per superstep; ping-pong h
// slots with compile-time rp in peeled steps.
__global__ __launch_bounds__(128, 1) void lstm_pipeline_kernel(
    const float* __restrict__ x,
    const float* __restrict__ Wih0, const float* __restrict__ Whh0,
    const float* __restrict__ bih0, const float* __restrict__ bhh0,
    const float* __restrict__ Wih1, const float* __restrict__ Whh1,
    const float* __restrict__ bih1, const float* __restrict__ bhh1,
    const float* __restrict__ Wih2, const float* __restrict__ Whh2,
    const float* __restrict__ bih2, const float* __restrict__ bhh2,
    const float* __restrict__ W1, const float* __restrict__ b1,
    const float* __restrict__ W2, const float* __restrict__ b2,
    float* __restrict__ hidden_out,   // [3, 512, 33]
    float* __restrict__ outp)         // [3, 512, 18]
{
    __shared__ __align__(16) _Float16 xst[TT + 2][XPAD];   // staged x, 65.6 KB
    __shared__ __align__(16) _Float16 buf[2][NL + 1][HSLOT];
    __shared__ float hfin[NL][HH + 1];   // final h per layer (fp32, fused MLP)
    __shared__ float h1s[NL][4 * OO];    // MLP hidden

    const int tid = threadIdx.x;
    const int bg  = blockIdx.x;

    for (int i = tid; i < 2 * (NL + 1) * HSLOT; i += 128)
        ((_Float16*)buf)[i] = (_Float16)0.0f;

    // ---- x staging: pad cells zeroed; real cells filled (disjoint writes,
    //      no barrier needed between the two loops) ----
    for (int f = tid; f < (TT + 2) * XPAD; f += 128) {
        const int i = f & (XPAD - 1);
        const int t = f >> 4;
        if (i >= II || t >= TT) ((_Float16*)xst)[f] = (_Float16)0.0f;
    }
    {
        const float* xblk = x + (size_t)bg * TT * II;
        const float4* xf4 = (const float4*)xblk;          // 22528 floats = 5632 f4
        for (int f4 = tid; f4 < (TT * II) / 4; f4 += 128) {
            const float4 v = xf4[f4];
            const int e0 = 4 * f4;
            #pragma unroll
            for (int e = 0; e < 4; ++e) {
                const int idx = e0 + e;
                const int t = idx / II;                   // magic-mul
                const int i = idx - t * II;
                xst[t][i] = (_Float16)((&v.x)[e]);
            }
        }
    }

    const bool comp = (tid < 99);
    const int  u    = tid;
    const int  l    = (u < 33) ? 0 : (u < 66) ? 1 : 2;
    const int  j    = u - 33 * l;

    // ---- per-lane weights: 4 gates x (input 34 + own 34) halves, named regs ----
    h8 z8 = {0,0,0,0,0,0,0,0};
    h2 z2 = {(_Float16)0.0f, (_Float16)0.0f};
    h8 x00=z8,x01=z8,x02=z8,x03=z8; h2 x0t=z2;   // gate i, input side (W_ih row)
    h8 x10=z8,x11=z8,x12=z8,x13=z8; h2 x1t=z2;   // gate f
    h8 x20=z8,x21=z8,x22=z8,x23=z8; h2 x2t=z2;   // gate g
    h8 x30=z8,x31=z8,x32=z8,x33=z8; h2 x3t=z2;   // gate o
    h8 h00=z8,h01=z8,h02=z8,h03=z8; h2 h0t=z2;   // gate i, own-h side (W_hh row)
    h8 h10=z8,h11=z8,h12=z8,h13=z8; h2 h1t=z2;
    h8 h20=z8,h21=z8,h22=z8,h23=z8; h2 h2t=z2;
    h8 h30=z8,h31=z8,h32=z8,h33=z8; h2 h3t=z2;
    float b0 = 0.0f, b1v = 0.0f, b2v = 0.0f, b3v = 0.0f;

    if (comp) {
        const float* bip = (l == 0) ? bih0 : (l == 1) ? bih1 : bih2;
        const float* bhp = (l == 0) ? bhh0 : (l == 1) ? bhh1 : bhh2;
        b0  = bip[0 * HH + j] + bhp[0 * HH + j];
        b1v = bip[1 * HH + j] + bhp[1 * HH + j];
        b2v = bip[2 * HH + j] + bhp[2 * HH + j];
        b3v = bip[3 * HH + j] + bhp[3 * HH + j];

        const float* Wi = (l == 0) ? Wih0 : (l == 1) ? Wih1 : Wih2;
        const float* Wh = (l == 0) ? Whh0 : (l == 1) ? Whh1 : Whh2;
        const int kin = (l == 0) ? II : HH;
        const float* r0 = Wi + (0 * HH + j) * kin;
        const float* r1 = Wi + (1 * HH + j) * kin;
        const float* r2 = Wi + (2 * HH + j) * kin;
        const float* r3 = Wi + (3 * HH + j) * kin;
        x00=gldh8(r0,0,kin); x01=gldh8(r0,8,kin); x02=gldh8(r0,16,kin); x03=gldh8(r0,24,kin); x0t=gldh2(r0,32,kin);
        x10=gldh8(r1,0,kin); x11=gldh8(r1,8,kin); x12=gldh8(r1,16,kin); x13=gldh8(r1,24,kin); x1t=gldh2(r1,32,kin);
        x20=gldh8(r2,0,kin); x21=gldh8(r2,8,kin); x22=gldh8(r2,16,kin); x23=gldh8(r2,24,kin); x2t=gldh2(r2,32,kin);
        x30=gldh8(r3,0,kin); x31=gldh8(r3,8,kin); x32=gldh8(r3,16,kin); x33=gldh8(r3,24,kin); x3t=gldh2(r3,32,kin);
        const float* s0 = Wh + (0 * HH + j) * HH;
        const float* s1 = Wh + (1 * HH + j) * HH;
        const float* s2 = Wh + (2 * HH + j) * HH;
        const float* s3 = Wh + (3 * HH + j) * HH;
        h00=gldh8(s0,0,HH); h01=gldh8(s0,8,HH); h02=gldh8(s0,16,HH); h03=gldh8(s0,24,HH); h0t=gldh2(s0,32,HH);
        h10=gldh8(s1,0,HH); h11=gldh8(s1,8,HH); h12=gldh8(s1,16,HH); h13=gldh8(s1,24,HH); h1t=gldh2(s1,32,HH);
        h20=gldh8(s2,0,HH); h21=gldh8(s2,8,HH); h22=gldh8(s2,16,HH); h23=gldh8(s2,24,HH); h2t=gldh2(s2,32,HH);
        h30=gldh8(s3,0,HH); h31=gldh8(s3,8,HH); h32=gldh8(s3,16,HH); h33=gldh8(s3,24,HH); h3t=gldh2(s3,32,HH);
    }

    __syncthreads();

    float c = 0.0f;

    // hoisted ping-pong pointers (compile-time selected in peeled steps)
    const _Float16* rin[2]  = { &buf[0][l][0],     &buf[1][l][0] };      // h input (l>0)
    const _Float16* rown[2] = { &buf[0][l + 1][0], &buf[1][l + 1][0] };  // own-h vec
    _Float16*       wrp[2]  = { &buf[0][l + 1][j], &buf[1][l + 1][j] };
    const _Float16* xst0    = &xst[0][0];

    // one superstep; rp/check/out are compile-time constants at call sites
    auto step = [&](int s, int rp, bool check, bool out)
        __attribute__((always_inline)) {
        const int wp = rp ^ 1;
        const bool active = check ? (comp && (s >= l) && (s - l < TT)) : comp;
        if (active) {
            // layer-0 reads its timestep row straight from staged x (the
            // overhang halves vi2/vi3/vit land in later rows / pad -- finite
            // values times zero weights); layers 1,2 read the h ping-pong.
            const _Float16* ri = (l == 0) ? (xst0 + (s << 4)) : rin[rp];
            const h8* VI = (const h8*)ri;
            const h8 vi0 = VI[0], vi1 = VI[1], vi2 = VI[2], vi3 = VI[3];
            const h2 vit = *(const h2*)(ri + 32);
            const h8* VO = (const h8*)rown[rp];
            const h8 vo0 = VO[0], vo1 = VO[1], vo2 = VO[2], vo3 = VO[3];
            const h2 vot = *(const h2*)(rown[rp] + 32);

            // ---- single MAC phase: 8 independent 17-deep fdot2 chains ----
            float a0i = b0, a1i = b1v, a2i = b2v, a3i = b3v;
            float a0h = 0.0f, a1h = 0.0f, a2h = 0.0f, a3h = 0.0f;
            DUOQ(vi0, vo0, x00, x10, x20, x30, h00, h10, h20, h30);
            DUOQ(vi1, vo1, x01, x11, x21, x31, h01, h11, h21, h31);
            DUOQ(vi2, vo2, x02, x12, x22, x32, h02, h12, h22, h32);
            DUOQ(vi3, vo3, x03, x13, x23, x33, h03, h13, h23, h33);
            FD(a0i, vit, x0t); FD(a1i, vit, x1t);
            FD(a2i, vit, x2t); FD(a3i, vit, x3t);
            FD(a0h, vot, h0t); FD(a1h, vot, h1t);
            FD(a2h, vot, h2t); FD(a3h, vot, h3t);

            const float s0 = a0i + a0h;   // gate i
            const float s1 = a1i + a1h;   // gate f
            const float s2 = a2i + a2h;   // gate g
            const float s3 = a3i + a3h;   // gate o

            // ---- tail: 4 independent trans chains, then the c/h chain ----
            const float ig = sigm_f(s0);
            const float fg = sigm_f(s1);
            const float gg = tanh_f(s2);
            const float og = sigm_f(s3);
            c = __builtin_fmaf(fg, c, ig * gg);
            const float hnew = og * tanh_f(c);

            *wrp[wp] = (_Float16)hnew;
            if (out && (s - l == TT - 1)) {
                hidden_out[((size_t)l * BB + bg) * HH + j] = hnew;
                hfin[l][j] = hnew;
            }
        }
        __syncthreads();
    };

    // prologue (pipeline fill, masked)
    step(0, 0, true, false);
    step(1, 1, true, false);
    // steady state: s = 2..2043 as constant-rp pairs (no checks, no outputs)
    for (int s = 2; s < TT - 4; s += 2) {
        step(s,     0, false, false);
        step(s + 1, 1, false, false);
    }
    // tail of steady state + epilogue (drain + final-h outputs)
    step(TT - 4, 0, false, false);   // s=2044
    step(TT - 3, 1, false, false);   // s=2045
    step(TT - 2, 0, false, false);   // s=2046
    step(TT - 1, 1, false, true);    // s=2047: l0 writes hT
    step(TT,     0, true,  true);    // s=2048: l1 writes hT
    step(TT + 1, 1, true,  true);    // s=2049: l2 writes hT

    // ---- fused MLP head (hfin visible after the last step's barrier) ----
    // h1 = gelu_exact(hfin @ W1^T + b1) [3,72]; out = h1 @ W2^T + b2 [3,18]
    if (tid < 4 * OO) {                   // 72 threads x 3 layers
        #pragma unroll
        for (int ml = 0; ml < NL; ++ml) {
            float a = b1[tid];
            #pragma unroll
            for (int k = 0; k < HH; ++k) a += hfin[ml][k] * W1[tid * HH + k];
            h1s[ml][tid] = 0.5f * a * (1.0f + erff(a * 0.70710678118654752f));
        }
    }
    __syncthreads();
    if (tid < NL * OO) {                  // 54 threads
        const int ol = tid / OO, o = tid % OO;
        float a = b2[o];
        #pragma unroll
        for (int m = 0; m < 4 * OO; ++m) a += h1s[ol][m] * W2[o * (4 * OO) + m];
        outp[((size_t)ol * BB + bg) * OO + o] = a;
    }
}

extern "C" void kernel_launch(void* const* d_in, const int* in_sizes, int n_in,
                              void* d_out, int out_size, void* d_ws, size_t ws_size,
                              hipStream_t stream) {
    const float* x    = (const float*)d_in[0];
    const float* Wih0 = (const float*)d_in[1];
    const float* Whh0 = (const float*)d_in[2];
    const float* bih0 = (const float*)d_in[3];
    const float* bhh0 = (const float*)d_in[4];
    const float* Wih1 = (const float*)d_in[5];
    const float* Whh1 = (const float*)d_in[6];
    const float* bih1 = (const float*)d_in[7];
    const float* bhh1 = (const float*)d_in[8];
    const float* Wih2 = (const float*)d_in[9];
    const float* Whh2 = (const float*)d_in[10];
    const float* bih2 = (const float*)d_in[11];
    const float* bhh2 = (const float*)d_in[12];
    const float* W1   = (const float*)d_in[13];
    const float* b1   = (const float*)d_in[14];
    const float* W2   = (const float*)d_in[15];
    const float* b2   = (const float*)d_in[16];

    float* out    = (float*)d_out;                 // [3,512,18] = 27648 floats
    float* hidden = out + NL * BB * OO;            // [3,512,33] = 50688 floats

    lstm_pipeline_kernel<<<BB, 128, 0, stream>>>(
        x, Wih0, Whh0, bih0, bhh0, Wih1, Whh1, bih1, bhh1,
        Wih2, Whh2, bih2, bhh2, W1, b1, W2, b2, hidden, out);
}